// Round 25
// baseline (86.554 us; speedup 1.0000x reference)
//
#include <hip/hip_runtime.h>

typedef __attribute__((ext_vector_type(8))) short bf16x8;
typedef __attribute__((ext_vector_type(4))) float f32x4;

#define HWSZ 65536

__device__ inline unsigned to_bf16u(float f) {
    union { float f; unsigned u; } c; c.f = f;
    unsigned u = c.u;
    return (u + 0x7fffu + ((u >> 16) & 1u)) >> 16;   // round-nearest-even
}

// packed fp32x2 -> bf16x2 (RNE), low word = lo
__device__ inline unsigned cvt_pk_bf16(float lo, float hi) {
    unsigned r;
    asm("v_cvt_pk_bf16_f32 %0, %1, %2" : "=v"(r) : "v"(lo), "v"(hi));
    return r;
}

// Weights fp32 [co][ci][9] -> bf16 swizzled wsw [chunk][coh][kpos][co32][4 slot][8]
__global__ void wcvt(const float* __restrict__ wgt, unsigned short* __restrict__ wsw) {
    int idx = blockIdx.x * 256 + threadIdx.x;       // 36864 total
    int co   = idx / 576;
    int rem  = idx - co * 576;
    int ci   = rem / 9;
    int kpos = rem - ci * 9;
    unsigned short v = (unsigned short)to_bf16u(wgt[idx]);
    int coh = co >> 5, col = co & 31;
    int chunk = ci >> 5, cil = ci & 31;
    int slot = (cil >> 3) ^ ((col >> 1) & 3);
    wsw[(((chunk * 2 + coh) * 9 + kpos) * 32 + col) * 32 + slot * 8 + (cil & 7)] = v;
}

__global__ __launch_bounds__(512, 4) void maskconv_mfma(
    const float* __restrict__ x, const int* __restrict__ mask,
    const unsigned short* __restrict__ wsw, const float* __restrict__ bias,
    float* __restrict__ out)
{
    __shared__ unsigned short xs[352 * 32];   // 22528 B: [pixel 10x34 (+pad)][ci32], swizzled
    __shared__ unsigned short wl[36 * 512];   // 36864 B: [coh][kpos][co32][ci32], swizzled (1 chunk)

    const int tid  = threadIdx.x;
    const int lane = tid & 63;
    const int wv   = tid >> 6;          // wave 0..7
    const int wr   = wv & 3;            // row-group: rows wr*2..wr*2+1
    const int coh  = wv >> 2;           // co-half this wave computes
    const int l15  = lane & 15;
    const int l4   = lane >> 4;
    const int oct  = wv & 3;            // ci-octet this wave stages

    // XCD band swizzle: XCD (= bx&7) owns a contiguous band of 4 tile-rows ->
    // halo-sharing neighbors are co-XCD-L2.  (256 % 8 == 0 so by doesn't shift it)
    const int bx   = blockIdx.x;        // 0..255
    const int tile = ((bx & 7) << 5) | (bx >> 3);
    const int tw = (tile & 7) * 32;
    const int th = (tile >> 3) * 8;
    const int b  = blockIdx.y;

    const float* xb = x + (size_t)b * 64 * HWSZ;
    char* xsb = (char*)xs;
    char* wlb = (char*)wl;

    f32x4 acc[4][2];
    #pragma unroll
    for (int f = 0; f < 4; ++f)
        #pragma unroll
        for (int j = 0; j < 2; ++j)
            acc[f][j] = (f32x4){0.f, 0.f, 0.f, 0.f};

    // ---- stage-task geometry: wave stages octet `oct`, passes p = coh + 2q, q=0..2 ----
    int off[3];
    int dst[3];
    unsigned vmask = 0;   // bit q: pixel in-image (else zeros)
    unsigned wmask = 0;   // bit q: slot exists (pi < 340)
    #pragma unroll
    for (int q = 0; q < 3; ++q) {
        int p  = coh + 2 * q;
        int pi = p * 64 + lane;         // valid < 340
        int r   = pi / 34;
        int lcv = pi - r * 34;
        int gr = th - 1 + r;
        int gc = tw - 1 + lcv;
        unsigned inb = (pi < 340) & ((unsigned)gr < 256u) & ((unsigned)gc < 256u);
        off[q] = inb ? (gr * 256 + gc) : 0;
        vmask |= inb << q;
        wmask |= (unsigned)(pi < 340) << q;
        int s = (lcv >> 1) & 3;
        dst[q] = pi * 64 + ((oct ^ s) << 4);
    }

    // fused stage: fp32 NCHW loads -> v_cvt_pk_bf16_f32 -> swizzled LDS; 2-deep pipeline
    auto stage_x = [&](int c) {
        const float* srcc = xb + (size_t)(c * 32 + oct * 8) * HWSZ;
        float va[8], vb[8];
        #pragma unroll
        for (int k = 0; k < 8; ++k) va[k] = srcc[(size_t)k * HWSZ + off[0]];
        #pragma unroll
        for (int q = 0; q < 3; ++q) {
            if (q < 2) {                 // prefetch next task
                #pragma unroll
                for (int k = 0; k < 8; ++k) {
                    float t = srcc[(size_t)k * HWSZ + off[q + 1]];
                    if (q == 0) vb[k] = t; else va[k] = t;
                }
            }
            if ((wmask >> q) & 1u) {     // write whenever pixel slot exists (zeros if OOB halo)
                unsigned z = ((vmask >> q) & 1u) ? 0xffffffffu : 0u;
                unsigned u[4];
                #pragma unroll
                for (int k = 0; k < 4; ++k) {
                    float lo = (q == 1) ? vb[2 * k]     : va[2 * k];
                    float hi = (q == 1) ? vb[2 * k + 1] : va[2 * k + 1];
                    u[k] = cvt_pk_bf16(lo, hi) & z;
                }
                *(uint4*)(xsb + dst[q]) = (uint4){u[0], u[1], u[2], u[3]};
            }
        }
    };

    auto stage_wl = [&](int c) {
        const unsigned short* base = wsw + c * 18432;
        #pragma unroll
        for (int q = 0; q < 5; ++q) {
            int i = wv + 8 * q;
            if (i < 36) {
                const unsigned short* g = base + i * 512 + lane * 8;   // per-lane source
                unsigned short* l = wl + i * 512;
                __builtin_amdgcn_global_load_lds(
                    (const __attribute__((address_space(1))) void*)(const void*)g,
                    (__attribute__((address_space(3))) void*)(void*)l, 16, 0, 0);
            }
        }
    };

    // kw-outer MFMA: 8 distinct A-frags per kw cached in regs (reads 54 -> 42 per chunk)
    auto do_mfma = [&]() {
        #pragma unroll
        for (int kw = 0; kw < 3; ++kw) {
            bf16x8 af[4][2];             // [rp = (f>>1)+kh][wh = f&1], all static indices
            #pragma unroll
            for (int rp = 0; rp < 4; ++rp)
                #pragma unroll
                for (int wh = 0; wh < 2; ++wh) {
                    int lc = wh * 16 + l15 + kw;
                    int s  = (lc >> 1) & 3;
                    af[rp][wh] = *(const bf16x8*)(xsb + ((wr * 2 + rp) * 34 + lc) * 64 + ((l4 ^ s) << 4));
                }
            #pragma unroll
            for (int kh = 0; kh < 3; ++kh) {
                const int kpos = kh * 3 + kw;
                bf16x8 bfrag[2];
                #pragma unroll
                for (int j = 0; j < 2; ++j) {
                    int col = j * 16 + l15;
                    int sl = l4 ^ ((col >> 1) & 3);
                    bfrag[j] = *(const bf16x8*)(wlb + coh * 18432 + (kpos * 32 + col) * 64 + (sl << 4));
                }
                #pragma unroll
                for (int f = 0; f < 4; ++f) {
                    #pragma unroll
                    for (int j = 0; j < 2; ++j)
                        acc[f][j] = __builtin_amdgcn_mfma_f32_16x16x32_bf16(
                            af[(f >> 1) + kh][f & 1], bfrag[j], acc[f][j], 0, 0, 0);
                }
            }
        }
    };

    stage_wl(0);
    stage_x(0);
    __syncthreads();            // xs+wl chunk0 ready (drains vmcnt+lgkm)
    do_mfma();
    __syncthreads();            // done reading chunk0
    stage_wl(1);
    stage_x(1);
    __syncthreads();
    do_mfma();

    // ---- epilogue: bias (fp32) + mask, paired float4 stores (full 128B lines) ----
    const int* mb = mask + (size_t)b * HWSZ;
    float bv[2];
    #pragma unroll
    for (int j = 0; j < 2; ++j) bv[j] = bias[coh * 32 + j * 16 + l15];

    #pragma unroll
    for (int rr = 0; rr < 2; ++rr) {
        int h   = th + wr * 2 + rr;
        int wq0 = tw + l4 * 4;
        int4 mv0 = *(const int4*)(mb + h * 256 + wq0);
        int4 mv1 = *(const int4*)(mb + h * 256 + wq0 + 16);
        float m00 = (float)mv0.x, m01 = (float)mv0.y, m02 = (float)mv0.z, m03 = (float)mv0.w;
        float m10 = (float)mv1.x, m11 = (float)mv1.y, m12 = (float)mv1.z, m13 = (float)mv1.w;
        #pragma unroll
        for (int j = 0; j < 2; ++j) {
            int co = coh * 32 + j * 16 + l15;
            float* obase = out + (((size_t)(b * 64 + co)) << 16) + h * 256;
            f32x4 a0 = acc[rr * 2 + 0][j];   // cols wq0..wq0+3
            f32x4 a1 = acc[rr * 2 + 1][j];   // cols wq0+16..+19
            float4 o0, o1;
            o0.x = (a0.x + bv[j]) * m00;
            o0.y = (a0.y + bv[j]) * m01;
            o0.z = (a0.z + bv[j]) * m02;
            o0.w = (a0.w + bv[j]) * m03;
            o1.x = (a1.x + bv[j]) * m10;
            o1.y = (a1.y + bv[j]) * m11;
            o1.z = (a1.z + bv[j]) * m12;
            o1.w = (a1.w + bv[j]) * m13;
            *(float4*)(obase + wq0) = o0;
            *(float4*)(obase + wq0 + 16) = o1;
        }
    }
}

extern "C" void kernel_launch(void* const* d_in, const int* in_sizes, int n_in,
                              void* d_out, int out_size, void* d_ws, size_t ws_size,
                              hipStream_t stream) {
    const float* x    = (const float*)d_in[0];
    const int*   mask = (const int*)d_in[1];
    const float* wgt  = (const float*)d_in[2];
    const float* bias = (const float*)d_in[3];
    float* out = (float*)d_out;
    unsigned short* wsw = (unsigned short*)d_ws;    // 73728 B used

    wcvt<<<dim3(144), dim3(256), 0, stream>>>(wgt, wsw);
    maskconv_mfma<<<dim3(256, 8), dim3(512), 0, stream>>>(x, mask, wsw, bias, out);
}

// Round 26
// 79.293 us; speedup vs baseline: 1.0916x; 1.0916x over previous
//
#include <hip/hip_runtime.h>

typedef __attribute__((ext_vector_type(8))) short bf16x8;
typedef __attribute__((ext_vector_type(4))) float f32x4;

#define HWSZ 65536

__device__ inline unsigned to_bf16u(float f) {
    union { float f; unsigned u; } c; c.f = f;
    unsigned u = c.u;
    return (u + 0x7fffu + ((u >> 16) & 1u)) >> 16;   // round-nearest-even
}

// packed fp32x2 -> bf16x2 (RNE), low word = lo
__device__ inline unsigned cvt_pk_bf16(float lo, float hi) {
    unsigned r;
    asm("v_cvt_pk_bf16_f32 %0, %1, %2" : "=v"(r) : "v"(lo), "v"(hi));
    return r;
}

// Weights fp32 [co][ci][9] -> bf16 swizzled wsw [chunk][coh][kpos][co32][4 slot][8]
__global__ void wcvt(const float* __restrict__ wgt, unsigned short* __restrict__ wsw) {
    int idx = blockIdx.x * 256 + threadIdx.x;       // 36864 total
    int co   = idx / 576;
    int rem  = idx - co * 576;
    int ci   = rem / 9;
    int kpos = rem - ci * 9;
    unsigned short v = (unsigned short)to_bf16u(wgt[idx]);
    int coh = co >> 5, col = co & 31;
    int chunk = ci >> 5, cil = ci & 31;
    int slot = (cil >> 3) ^ ((col >> 1) & 3);
    wsw[(((chunk * 2 + coh) * 9 + kpos) * 32 + col) * 32 + slot * 8 + (cil & 7)] = v;
}

__global__ __launch_bounds__(512, 4) void maskconv_mfma(
    const float* __restrict__ x, const int* __restrict__ mask,
    const unsigned short* __restrict__ wsw, const float* __restrict__ bias,
    float* __restrict__ out)
{
    __shared__ unsigned short xs[352 * 32];   // 22528 B: [pixel 10x34 (+pad)][ci32], swizzled
    __shared__ unsigned short wl[36 * 512];   // 36864 B: [coh][kpos][co32][ci32], swizzled (1 chunk)

    const int tid  = threadIdx.x;
    const int lane = tid & 63;
    const int wv   = tid >> 6;          // wave 0..7
    const int wr   = wv & 3;            // row-group: rows wr*2..wr*2+1
    const int coh  = wv >> 2;           // co-half this wave computes
    const int l15  = lane & 15;
    const int l4   = lane >> 4;
    const int oct  = wv & 3;            // ci-octet this wave stages

    // XCD band swizzle: XCD (= bx&7) owns a contiguous band of 4 tile-rows ->
    // halo-sharing neighbors are co-XCD-L2.  (256 % 8 == 0 so by doesn't shift it)
    const int bx   = blockIdx.x;        // 0..255
    const int tile = ((bx & 7) << 5) | (bx >> 3);
    const int tw = (tile & 7) * 32;
    const int th = (tile >> 3) * 8;
    const int b  = blockIdx.y;

    const float* xb = x + (size_t)b * 64 * HWSZ;
    char* xsb = (char*)xs;
    char* wlb = (char*)wl;

    f32x4 acc[4][2];
    #pragma unroll
    for (int f = 0; f < 4; ++f)
        #pragma unroll
        for (int j = 0; j < 2; ++j)
            acc[f][j] = (f32x4){0.f, 0.f, 0.f, 0.f};

    // ---- stage-task geometry: wave stages octet `oct`, passes p = coh + 2q, q=0..2 ----
    int off[3];
    int dst[3];
    unsigned vmask = 0;   // bit q: pixel in-image (else zeros)
    unsigned wmask = 0;   // bit q: slot exists (pi < 340)
    #pragma unroll
    for (int q = 0; q < 3; ++q) {
        int p  = coh + 2 * q;
        int pi = p * 64 + lane;         // valid < 340
        int r   = pi / 34;
        int lcv = pi - r * 34;
        int gr = th - 1 + r;
        int gc = tw - 1 + lcv;
        unsigned inb = (pi < 340) & ((unsigned)gr < 256u) & ((unsigned)gc < 256u);
        off[q] = inb ? (gr * 256 + gc) : 0;
        vmask |= inb << q;
        wmask |= (unsigned)(pi < 340) << q;
        int s = (lcv >> 1) & 3;
        dst[q] = pi * 64 + ((oct ^ s) << 4);
    }

    // fused stage: fp32 NCHW loads -> v_cvt_pk_bf16_f32 -> swizzled LDS; 2-deep pipeline
    auto stage_x = [&](int c) {
        const float* srcc = xb + (size_t)(c * 32 + oct * 8) * HWSZ;
        float va[8], vb[8];
        #pragma unroll
        for (int k = 0; k < 8; ++k) va[k] = srcc[(size_t)k * HWSZ + off[0]];
        #pragma unroll
        for (int q = 0; q < 3; ++q) {
            if (q < 2) {                 // prefetch next task
                #pragma unroll
                for (int k = 0; k < 8; ++k) {
                    float t = srcc[(size_t)k * HWSZ + off[q + 1]];
                    if (q == 0) vb[k] = t; else va[k] = t;
                }
            }
            if ((wmask >> q) & 1u) {     // write whenever pixel slot exists (zeros if OOB halo)
                unsigned z = ((vmask >> q) & 1u) ? 0xffffffffu : 0u;
                unsigned u[4];
                #pragma unroll
                for (int k = 0; k < 4; ++k) {
                    float lo = (q == 1) ? vb[2 * k]     : va[2 * k];
                    float hi = (q == 1) ? vb[2 * k + 1] : va[2 * k + 1];
                    u[k] = cvt_pk_bf16(lo, hi) & z;
                }
                *(uint4*)(xsb + dst[q]) = (uint4){u[0], u[1], u[2], u[3]};
            }
        }
    };

    auto stage_wl = [&](int c) {
        const unsigned short* base = wsw + c * 18432;
        #pragma unroll
        for (int q = 0; q < 5; ++q) {
            int i = wv + 8 * q;
            if (i < 36) {
                const unsigned short* g = base + i * 512 + lane * 8;   // per-lane source
                unsigned short* l = wl + i * 512;
                __builtin_amdgcn_global_load_lds(
                    (const __attribute__((address_space(1))) void*)(const void*)g,
                    (__attribute__((address_space(3))) void*)(void*)l, 16, 0, 0);
            }
        }
    };

    auto do_mfma = [&]() {
        #pragma unroll
        for (int kh = 0; kh < 3; ++kh) {
            #pragma unroll
            for (int kw = 0; kw < 3; ++kw) {
                const int kpos = kh * 3 + kw;
                bf16x8 bfrag[2];
                #pragma unroll
                for (int j = 0; j < 2; ++j) {
                    int col = j * 16 + l15;
                    int sl = l4 ^ ((col >> 1) & 3);
                    bfrag[j] = *(const bf16x8*)(wlb + coh * 18432 + (kpos * 32 + col) * 64 + (sl << 4));
                }
                #pragma unroll
                for (int f = 0; f < 4; ++f) {
                    int lc = (f & 1) * 16 + l15 + kw;
                    int r  = wr * 2 + (f >> 1) + kh;
                    int s  = (lc >> 1) & 3;
                    bf16x8 afrag = *(const bf16x8*)(xsb + (r * 34 + lc) * 64 + ((l4 ^ s) << 4));
                    #pragma unroll
                    for (int j = 0; j < 2; ++j)
                        acc[f][j] = __builtin_amdgcn_mfma_f32_16x16x32_bf16(
                            afrag, bfrag[j], acc[f][j], 0, 0, 0);
                }
            }
        }
    };

    stage_wl(0);
    stage_x(0);
    __syncthreads();            // xs+wl chunk0 ready (drains vmcnt+lgkm)
    do_mfma();
    __syncthreads();            // done reading chunk0
    stage_wl(1);
    stage_x(1);
    __syncthreads();
    do_mfma();

    // ---- epilogue: bias (fp32) + mask, paired float4 stores (full 128B lines) ----
    const int* mb = mask + (size_t)b * HWSZ;
    float bv[2];
    #pragma unroll
    for (int j = 0; j < 2; ++j) bv[j] = bias[coh * 32 + j * 16 + l15];

    #pragma unroll
    for (int rr = 0; rr < 2; ++rr) {
        int h   = th + wr * 2 + rr;
        int wq0 = tw + l4 * 4;
        int4 mv0 = *(const int4*)(mb + h * 256 + wq0);
        int4 mv1 = *(const int4*)(mb + h * 256 + wq0 + 16);
        float m00 = (float)mv0.x, m01 = (float)mv0.y, m02 = (float)mv0.z, m03 = (float)mv0.w;
        float m10 = (float)mv1.x, m11 = (float)mv1.y, m12 = (float)mv1.z, m13 = (float)mv1.w;
        #pragma unroll
        for (int j = 0; j < 2; ++j) {
            int co = coh * 32 + j * 16 + l15;
            float* obase = out + (((size_t)(b * 64 + co)) << 16) + h * 256;
            f32x4 a0 = acc[rr * 2 + 0][j];   // cols wq0..wq0+3
            f32x4 a1 = acc[rr * 2 + 1][j];   // cols wq0+16..+19
            float4 o0, o1;
            o0.x = (a0.x + bv[j]) * m00;
            o0.y = (a0.y + bv[j]) * m01;
            o0.z = (a0.z + bv[j]) * m02;
            o0.w = (a0.w + bv[j]) * m03;
            o1.x = (a1.x + bv[j]) * m10;
            o1.y = (a1.y + bv[j]) * m11;
            o1.z = (a1.z + bv[j]) * m12;
            o1.w = (a1.w + bv[j]) * m13;
            *(float4*)(obase + wq0) = o0;
            *(float4*)(obase + wq0 + 16) = o1;
        }
    }
}

extern "C" void kernel_launch(void* const* d_in, const int* in_sizes, int n_in,
                              void* d_out, int out_size, void* d_ws, size_t ws_size,
                              hipStream_t stream) {
    const float* x    = (const float*)d_in[0];
    const int*   mask = (const int*)d_in[1];
    const float* wgt  = (const float*)d_in[2];
    const float* bias = (const float*)d_in[3];
    float* out = (float*)d_out;
    unsigned short* wsw = (unsigned short*)d_ws;    // 73728 B used

    wcvt<<<dim3(144), dim3(256), 0, stream>>>(wgt, wsw);
    maskconv_mfma<<<dim3(256, 8), dim3(512), 0, stream>>>(x, mask, wsw, bias, out);
}

// Round 27
// 74.958 us; speedup vs baseline: 1.1547x; 1.0578x over previous
//
#include <hip/hip_runtime.h>

typedef __attribute__((ext_vector_type(8))) short bf16x8;
typedef __attribute__((ext_vector_type(4))) float f32x4;

#define HWSZ 65536

__device__ inline unsigned to_bf16u(float f) {
    union { float f; unsigned u; } c; c.f = f;
    unsigned u = c.u;
    return (u + 0x7fffu + ((u >> 16) & 1u)) >> 16;   // round-nearest-even
}

// packed fp32x2 -> bf16x2 (RNE), low word = lo
__device__ inline unsigned cvt_pk_bf16(float lo, float hi) {
    unsigned r;
    asm("v_cvt_pk_bf16_f32 %0, %1, %2" : "=v"(r) : "v"(lo), "v"(hi));
    return r;
}

// Weights fp32 [co][ci][9] -> bf16 swizzled wsw [chunk][coh][kpos][co32][4 slot][8]
__global__ void wcvt(const float* __restrict__ wgt, unsigned short* __restrict__ wsw) {
    int idx = blockIdx.x * 256 + threadIdx.x;       // 36864 total
    int co   = idx / 576;
    int rem  = idx - co * 576;
    int ci   = rem / 9;
    int kpos = rem - ci * 9;
    unsigned short v = (unsigned short)to_bf16u(wgt[idx]);
    int coh = co >> 5, col = co & 31;
    int chunk = ci >> 5, cil = ci & 31;
    int slot = (cil >> 3) ^ ((col >> 1) & 3);
    wsw[(((chunk * 2 + coh) * 9 + kpos) * 32 + col) * 32 + slot * 8 + (cil & 7)] = v;
}

__global__ __launch_bounds__(512, 4) void maskconv_mfma(
    const float* __restrict__ x, const int* __restrict__ mask,
    const unsigned short* __restrict__ wsw, const float* __restrict__ bias,
    float* __restrict__ out)
{
    __shared__ unsigned short xs[352 * 32];   // 22528 B: [pixel 10x34 (+pad)][ci32], swizzled
    __shared__ unsigned short wl[36 * 512];   // 36864 B: [coh][kpos][co32][ci32], swizzled (1 chunk)

    const int tid  = threadIdx.x;
    const int lane = tid & 63;
    const int wv   = tid >> 6;          // wave 0..7
    const int wr   = wv & 3;            // row-group: rows wr*2..wr*2+1
    const int coh  = wv >> 2;           // co-half this wave computes
    const int l15  = lane & 15;
    const int l4   = lane >> 4;
    const int oct  = wv & 3;            // ci-octet this wave stages

    // XCD band swizzle: XCD (= bx&7) owns a contiguous band of 4 tile-rows ->
    // halo-sharing neighbors are co-XCD-L2.  (256 % 8 == 0 so by doesn't shift it)
    const int bx   = blockIdx.x;        // 0..255
    const int tile = ((bx & 7) << 5) | (bx >> 3);
    const int tw = (tile & 7) * 32;
    const int th = (tile >> 3) * 8;
    const int b  = blockIdx.y;

    const float* xb = x + (size_t)b * 64 * HWSZ;
    char* xsb = (char*)xs;
    char* wlb = (char*)wl;

    f32x4 acc[4][2];
    #pragma unroll
    for (int f = 0; f < 4; ++f)
        #pragma unroll
        for (int j = 0; j < 2; ++j)
            acc[f][j] = (f32x4){0.f, 0.f, 0.f, 0.f};

    // ---- stage-task geometry: wave stages octet `oct`, passes p = coh + 2q, q=0..2 ----
    int off[3];
    int dst[3];
    unsigned vmask = 0;   // bit q: pixel in-image (else zeros)
    unsigned wmask = 0;   // bit q: slot exists (pi < 340)
    #pragma unroll
    for (int q = 0; q < 3; ++q) {
        int p  = coh + 2 * q;
        int pi = p * 64 + lane;         // valid < 340
        int r   = pi / 34;
        int lcv = pi - r * 34;
        int gr = th - 1 + r;
        int gc = tw - 1 + lcv;
        unsigned inb = (pi < 340) & ((unsigned)gr < 256u) & ((unsigned)gc < 256u);
        off[q] = inb ? (gr * 256 + gc) : 0;
        vmask |= inb << q;
        wmask |= (unsigned)(pi < 340) << q;
        int s = (lcv >> 1) & 3;
        dst[q] = pi * 64 + ((oct ^ s) << 4);
    }

    // fused stage: fp32 NCHW loads -> v_cvt_pk_bf16_f32 -> swizzled LDS; 2-deep pipeline
    auto stage_x = [&](int c) {
        const float* srcc = xb + (size_t)(c * 32 + oct * 8) * HWSZ;
        float va[8], vb[8];
        #pragma unroll
        for (int k = 0; k < 8; ++k) va[k] = srcc[(size_t)k * HWSZ + off[0]];
        #pragma unroll
        for (int q = 0; q < 3; ++q) {
            if (q < 2) {                 // prefetch next task
                #pragma unroll
                for (int k = 0; k < 8; ++k) {
                    float t = srcc[(size_t)k * HWSZ + off[q + 1]];
                    if (q == 0) vb[k] = t; else va[k] = t;
                }
            }
            if ((wmask >> q) & 1u) {     // write whenever pixel slot exists (zeros if OOB halo)
                unsigned z = ((vmask >> q) & 1u) ? 0xffffffffu : 0u;
                unsigned u[4];
                #pragma unroll
                for (int k = 0; k < 4; ++k) {
                    float lo = (q == 1) ? vb[2 * k]     : va[2 * k];
                    float hi = (q == 1) ? vb[2 * k + 1] : va[2 * k + 1];
                    u[k] = cvt_pk_bf16(lo, hi) & z;
                }
                *(uint4*)(xsb + dst[q]) = (uint4){u[0], u[1], u[2], u[3]};
            }
        }
    };

    auto stage_wl = [&](int c) {
        const unsigned short* base = wsw + c * 18432;
        #pragma unroll
        for (int q = 0; q < 5; ++q) {
            int i = wv + 8 * q;
            if (i < 36) {
                const unsigned short* g = base + i * 512 + lane * 8;   // per-lane source
                unsigned short* l = wl + i * 512;
                __builtin_amdgcn_global_load_lds(
                    (const __attribute__((address_space(1))) void*)(const void*)g,
                    (__attribute__((address_space(3))) void*)(void*)l, 16, 0, 0);
            }
        }
    };

    auto do_mfma = [&]() {
        #pragma unroll
        for (int kh = 0; kh < 3; ++kh) {
            #pragma unroll
            for (int kw = 0; kw < 3; ++kw) {
                const int kpos = kh * 3 + kw;
                bf16x8 bfrag[2];
                #pragma unroll
                for (int j = 0; j < 2; ++j) {
                    int col = j * 16 + l15;
                    int sl = l4 ^ ((col >> 1) & 3);
                    bfrag[j] = *(const bf16x8*)(wlb + coh * 18432 + (kpos * 32 + col) * 64 + (sl << 4));
                }
                #pragma unroll
                for (int f = 0; f < 4; ++f) {
                    int lc = (f & 1) * 16 + l15 + kw;
                    int r  = wr * 2 + (f >> 1) + kh;
                    int s  = (lc >> 1) & 3;
                    bf16x8 afrag = *(const bf16x8*)(xsb + (r * 34 + lc) * 64 + ((l4 ^ s) << 4));
                    #pragma unroll
                    for (int j = 0; j < 2; ++j)
                        acc[f][j] = __builtin_amdgcn_mfma_f32_16x16x32_bf16(
                            afrag, bfrag[j], acc[f][j], 0, 0, 0);
                }
            }
        }
    };

    stage_wl(0);
    stage_x(0);
    __syncthreads();            // xs+wl chunk0 ready (drains vmcnt+lgkm)
    do_mfma();
    __syncthreads();            // done reading chunk0
    stage_wl(1);
    stage_x(1);
    __syncthreads();
    do_mfma();

    // ---- epilogue: bias (fp32) + mask, paired NONTEMPORAL float4 stores ----
    // out is write-once/never-read: stream past L2/L3 so x stays L3-resident.
    const int* mb = mask + (size_t)b * HWSZ;
    float bv[2];
    #pragma unroll
    for (int j = 0; j < 2; ++j) bv[j] = bias[coh * 32 + j * 16 + l15];

    #pragma unroll
    for (int rr = 0; rr < 2; ++rr) {
        int h   = th + wr * 2 + rr;
        int wq0 = tw + l4 * 4;
        int4 mv0 = *(const int4*)(mb + h * 256 + wq0);
        int4 mv1 = *(const int4*)(mb + h * 256 + wq0 + 16);
        float m00 = (float)mv0.x, m01 = (float)mv0.y, m02 = (float)mv0.z, m03 = (float)mv0.w;
        float m10 = (float)mv1.x, m11 = (float)mv1.y, m12 = (float)mv1.z, m13 = (float)mv1.w;
        #pragma unroll
        for (int j = 0; j < 2; ++j) {
            int co = coh * 32 + j * 16 + l15;
            float* obase = out + (((size_t)(b * 64 + co)) << 16) + h * 256;
            f32x4 a0 = acc[rr * 2 + 0][j];   // cols wq0..wq0+3
            f32x4 a1 = acc[rr * 2 + 1][j];   // cols wq0+16..+19
            f32x4 o0, o1;
            o0.x = (a0.x + bv[j]) * m00;
            o0.y = (a0.y + bv[j]) * m01;
            o0.z = (a0.z + bv[j]) * m02;
            o0.w = (a0.w + bv[j]) * m03;
            o1.x = (a1.x + bv[j]) * m10;
            o1.y = (a1.y + bv[j]) * m11;
            o1.z = (a1.z + bv[j]) * m12;
            o1.w = (a1.w + bv[j]) * m13;
            __builtin_nontemporal_store(o0, (f32x4*)(obase + wq0));
            __builtin_nontemporal_store(o1, (f32x4*)(obase + wq0 + 16));
        }
    }
}

extern "C" void kernel_launch(void* const* d_in, const int* in_sizes, int n_in,
                              void* d_out, int out_size, void* d_ws, size_t ws_size,
                              hipStream_t stream) {
    const float* x    = (const float*)d_in[0];
    const int*   mask = (const int*)d_in[1];
    const float* wgt  = (const float*)d_in[2];
    const float* bias = (const float*)d_in[3];
    float* out = (float*)d_out;
    unsigned short* wsw = (unsigned short*)d_ws;    // 73728 B used

    wcvt<<<dim3(144), dim3(256), 0, stream>>>(wgt, wsw);
    maskconv_mfma<<<dim3(256, 8), dim3(512), 0, stream>>>(x, mask, wsw, bias, out);
}